// Round 14
// baseline (343.947 us; speedup 1.0000x reference)
//
#include <hip/hip_runtime.h>
#include <cstdint>
#include <cstddef>

typedef __bf16 bf16;
typedef float  f32x4  __attribute__((ext_vector_type(4)));
typedef __bf16 bf16x8 __attribute__((ext_vector_type(8)));
typedef __bf16 bf16x4 __attribute__((ext_vector_type(4)));

// ---------------- prep1: slots copy + W1T/W2T bf16 transposed [k][col] ----------
__global__ __launch_bounds__(256) void k_prep1(
    const float* __restrict__ slots_in, const float* __restrict__ W1,
    const float* __restrict__ W2,
    float* __restrict__ slots, bf16* __restrict__ W1T, bf16* __restrict__ W2T)
{
    const int i = blockIdx.x * 256 + threadIdx.x;
    if      (i <  65536) { slots[i] = slots_in[i]; }
    else if (i < 196608) { int j = i -  65536; int k = j >> 9, c = j & 511;
                           W1T[j] = (bf16)W1[c*256 + k]; }
    else if (i < 327680) { int j = i - 196608; int k = j >> 8, c = j & 255;
                           W2T[j] = (bf16)W2[c*512 + k]; }
}

// ---------------- prep2: Mqk (blocks 0-255) + Wxg = W_ih@Wv fp32 (blocks 256-1023) ----
__global__ __launch_bounds__(256) void k_prep2(
    const float* __restrict__ Wq, const float* __restrict__ Wk,
    const float* __restrict__ W_ih, const float* __restrict__ Wv,
    bf16* __restrict__ Mqk, float* __restrict__ Wxg)
{
    const int c = threadIdx.x;
    __shared__ float v[256];
    if (blockIdx.x < 256) {
        const int e = blockIdx.x;
        v[c] = Wq[(size_t)c*256 + e];
        __syncthreads();
        float a = 0.f;
#pragma unroll 8
        for (int d = 0; d < 256; ++d) a += v[d] * Wk[(size_t)d*256 + c];
        Mqk[(size_t)e*256 + c] = (bf16)(a * 0.0625f);
    } else {
        const int g = blockIdx.x - 256;
        v[c] = W_ih[(size_t)g*256 + c];
        __syncthreads();
        float a = 0.f;
#pragma unroll 8
        for (int d = 0; d < 256; ++d) a += v[d] * Wv[(size_t)d*256 + c];
        Wxg[(size_t)g*256 + c] = a;
    }
}

// ---------------- prep3: WgT[k][1536] = bf16( col<768 ? Wxg : W_hh ) ----------------
__global__ __launch_bounds__(256) void k_prep3(
    const float* __restrict__ Wxg, const float* __restrict__ W_hh,
    bf16* __restrict__ WgT)
{
    const int j = blockIdx.x * 256 + threadIdx.x;   // 0..393215
    const int k = j / 1536, col = j - k*1536;
    WgT[j] = (bf16)((col < 768) ? Wxg[(size_t)col*256 + k] : W_hh[(size_t)(col-768)*256 + k]);
}

// ---------------- K1: LayerNorm(inputs) -> xln bf16 ----------------
__global__ __launch_bounds__(256) void k_ln_in(
    const float* __restrict__ x, const float* __restrict__ g,
    const float* __restrict__ b, bf16* __restrict__ xln)
{
    const int wave = threadIdx.x >> 6, lane = threadIdx.x & 63;
    const size_t row = (size_t)blockIdx.x * 4 + wave;
    const float* xr = x + row * 256 + lane * 4;
    f32x4 v = *(const f32x4*)xr;
    float s  = v[0] + v[1] + v[2] + v[3];
    float ss = v[0]*v[0] + v[1]*v[1] + v[2]*v[2] + v[3]*v[3];
#pragma unroll
    for (int m = 32; m >= 1; m >>= 1) { s += __shfl_xor(s, m); ss += __shfl_xor(ss, m); }
    const float mean = s * (1.f/256.f);
    const float var  = ss * (1.f/256.f) - mean*mean;
    const float rstd = rsqrtf(var + 1e-5f);
    const f32x4 gg = *(const f32x4*)(g + lane*4);
    const f32x4 bb = *(const f32x4*)(b + lane*4);
    bf16x4 o;
#pragma unroll
    for (int e = 0; e < 4; ++e) o[e] = (bf16)((v[e]-mean)*rstd*gg[e] + bb[e]);
    *(bf16x4*)(xln + row*256 + lane*4) = o;
}

// gemv partial: 8 cols/thread, klen4*4 k's from wp (stride LDW), src via LDS broadcast
__device__ __forceinline__ void gemv8(const bf16* __restrict__ wp, int LDW,
                                      const float* __restrict__ sp, int klen4,
                                      float* __restrict__ ac)
{
#pragma unroll 8
    for (int k4 = 0; k4 < klen4; ++k4) {
        const f32x4 sv = *(const f32x4*)(sp + k4*4);
#pragma unroll
        for (int kk = 0; kk < 4; ++kk) {
            const bf16x8 w = *(const bf16x8*)(wp + (size_t)(k4*4+kk)*LDW);
#pragma unroll
            for (int j = 0; j < 8; ++j) ac[j] += sv[kk]*(float)w[j];
        }
    }
}

// ---------------- K_q0: q2 = LN_s(slots) @ Mqk (bf16 out) ; zero den. grid 256 ----
__global__ __launch_bounds__(256) void k_q0(
    const float* __restrict__ slots, const bf16* __restrict__ Mqk,
    const float* __restrict__ g_s, const float* __restrict__ b_s,
    bf16* __restrict__ q2bf, float* __restrict__ den)
{
    const int bs = blockIdx.x, tid = threadIdx.x;
    __shared__ float sln[256], part[2048], red[8];
    const float v0 = slots[(size_t)bs*256 + tid];
    if (tid == 0) den[bs] = 0.f;
    {
        float s1 = v0, s2 = v0*v0;
#pragma unroll
        for (int m = 32; m >= 1; m >>= 1) { s1 += __shfl_xor(s1, m); s2 += __shfl_xor(s2, m); }
        if ((tid & 63) == 0) { red[tid >> 6] = s1; red[4 + (tid >> 6)] = s2; }
    }
    __syncthreads();
    {
        const float mean = (red[0]+red[1]+red[2]+red[3])*(1.f/256.f);
        const float var  = (red[4]+red[5]+red[6]+red[7])*(1.f/256.f) - mean*mean;
        const float rstd = rsqrtf(var + 1e-5f);
        sln[tid] = (v0-mean)*rstd*g_s[tid] + b_s[tid];
    }
    __syncthreads();
    {
        const int g8 = tid & 31, ks = tid >> 5;
        float ac[8] = {0,0,0,0,0,0,0,0};
        gemv8(Mqk + (size_t)(ks*32)*256 + g8*8, 256, sln + ks*32, 8, ac);
#pragma unroll
        for (int j = 0; j < 8; ++j) part[ks*256 + g8*8 + j] = ac[j];
    }
    __syncthreads();
    {
        float a = 0.f;
#pragma unroll
        for (int k = 0; k < 8; ++k) a += part[k*256 + tid];
        q2bf[(size_t)bs*256 + tid] = (bf16)a;
    }
}

// ---------------- K_attn: single-pass fused attention over a 128-token tile ----
// grid (32 chunks, 32 b), 256 threads (4 waves x 32 tokens).
// Phase 1: MFMA logits with q2 in registers (r9); each loaded B-frag is ALSO
// stored to a swizzled LDS tile (r11/r12 swizzle). In-register softmax -> a
// straight to LDS. Phase 2: r13's scalar accumulate from the LDS tile.
__global__ __launch_bounds__(256) void k_attn(
    const bf16* __restrict__ xln, const bf16* __restrict__ q2bf,
    float* __restrict__ numpart, float* __restrict__ den,
    float* __restrict__ logits_out, int write_logits)
{
    const int chunk = blockIdx.x, b = blockIdx.y;
    const int tid = threadIdx.x;
    const int wv = tid >> 6, lane = tid & 63;
    const int sA = lane & 15;
    const int ko = (lane >> 4) * 8;
    __shared__ __align__(16) char  vbuf[128*512];   // [128 t][256 c] bf16, XOR swizzled
    __shared__           float alds[8][132];

    bf16x8 aq[8];
    if (sA < 8) {
#pragma unroll
        for (int kk = 0; kk < 8; ++kk)
            aq[kk] = *(const bf16x8*)(q2bf + (size_t)(b*8 + sA)*256 + kk*32 + ko);
    } else {
#pragma unroll
        for (int kk = 0; kk < 8; ++kk) aq[kk] = (bf16x8){0,0,0,0,0,0,0,0};
    }

    float dacc[4] = {0.f, 0.f, 0.f, 0.f};
#pragma unroll
    for (int it = 0; it < 2; ++it) {
        const int tl0 = wv*32 + it*16;            // tile-local token base
        const int t0  = chunk*128 + tl0;          // global token base
        const int tl  = tl0 + sA;
        char* vrow = vbuf + tl*512;
        const int swz = (tl & 7) << 4;
        f32x4 acc = {0.f, 0.f, 0.f, 0.f};
        const bf16* xp = xln + (size_t)(b*4096 + t0 + sA)*256 + ko;
#pragma unroll
        for (int kk = 0; kk < 8; ++kk) {
            const bf16x8 bfr = *(const bf16x8*)(xp + kk*32);
            *(bf16x8*)(vrow + ((2*(ko + kk*32)) ^ swz)) = bfr;
            acc = __builtin_amdgcn_mfma_f32_16x16x32_bf16(aq[kk], bfr, acc, 0, 0, 0);
        }
        // D layout: col = lane&15 = token, row = (lane>>4)*4 + r = slot (lanes 0-31).
        if (lane < 32) {
            float m1 = fmaxf(fmaxf(acc[0], acc[1]), fmaxf(acc[2], acc[3]));
            const float m2 = __shfl_xor(m1, 16);
            const float mx = fmaxf(m1, m2);
            float e[4], s4 = 0.f;
#pragma unroll
            for (int r = 0; r < 4; ++r) { e[r] = expf(acc[r] - mx); s4 += e[r]; }
            const float so = __shfl_xor(s4, 16);
            const float inv = 1.f / (s4 + so);
            const int tcol = tl0 + (lane & 15);
#pragma unroll
            for (int r = 0; r < 4; ++r) {
                const float av = e[r]*inv + 1e-8f;
                dacc[r] += av;
                alds[(lane >> 4)*4 + r][tcol] = av;
            }
            if (write_logits) {
#pragma unroll
                for (int r = 0; r < 4; ++r)
                    logits_out[(size_t)(b*8 + (lane >> 4)*4 + r)*4096 + chunk*128 + tcol] = acc[r];
            }
        }
    }
    if (lane < 32) {
#pragma unroll
        for (int r = 0; r < 4; ++r) {
            float v = dacc[r];
            v += __shfl_xor(v, 1); v += __shfl_xor(v, 2);
            v += __shfl_xor(v, 4); v += __shfl_xor(v, 8);
            if ((lane & 15) == 0) atomicAdd(&den[b*8 + (lane >> 4)*4 + r], v);
        }
    }
    __syncthreads();

    // phase 2: numpart[s][c] = sum_t a[s][t] * tile[t][c]
    {
        const int s2 = tid >> 5, u = tid & 31;
        float nacc[8] = {0,0,0,0,0,0,0,0};
#pragma unroll 8
        for (int t = 0; t < 128; ++t) {
            const bf16x8 x8 = *(const bf16x8*)(vbuf + t*512 + ((u*16) ^ ((t & 7) << 4)));
            const float a = alds[s2][t];
#pragma unroll
            for (int j = 0; j < 8; ++j) nacc[j] += a * (float)x8[j];
        }
        float* np = numpart + (((size_t)b*32 + chunk)*8 + s2)*256 + u*8;
        *(f32x4*)np       = (f32x4){nacc[0], nacc[1], nacc[2], nacc[3]};
        *(f32x4*)(np + 4) = (f32x4){nacc[4], nacc[5], nacc[6], nacc[7]};
    }
}

// ---------------- K_attnsw: attn_sw = (softmax+eps)/den ----------------
__global__ __launch_bounds__(256) void k_attnsw(
    const float* __restrict__ logits, const float* __restrict__ den,
    float* __restrict__ attn_out)
{
    const int chunk = blockIdx.x, b = blockIdx.y;
    const int t = chunk*256 + threadIdx.x;
    float l[8];
#pragma unroll
    for (int s = 0; s < 8; ++s) l[s] = logits[(size_t)(b*8 + s)*4096 + t];
    float mx = l[0];
#pragma unroll
    for (int s = 1; s < 8; ++s) mx = fmaxf(mx, l[s]);
    float e[8], sum = 0.f;
#pragma unroll
    for (int s = 0; s < 8; ++s) { e[s] = expf(l[s] - mx); sum += e[s]; }
    const float inv = 1.f/sum;
#pragma unroll
    for (int s = 0; s < 8; ++s)
        attn_out[(size_t)(b*8 + s)*4096 + t] = (e[s]*inv + 1e-8f) / den[b*8 + s];
}

// ---------------- K_slot: per-row slot chain; upd folded into WgT (Wxg) ----
__global__ __launch_bounds__(512) void k_slot(
    const float* __restrict__ numpart, float* __restrict__ den,
    float* __restrict__ slots,
    const bf16* __restrict__ WgT,
    const float* __restrict__ b_ih, const float* __restrict__ b_hh,
    const float* __restrict__ g_m, const float* __restrict__ b_m,
    const bf16* __restrict__ W1T, const float* __restrict__ b1,
    const bf16* __restrict__ W2T, const float* __restrict__ b2,
    const bf16* __restrict__ Mqk,
    const float* __restrict__ g_s, const float* __restrict__ b_s,
    bf16* __restrict__ q2bf, float* __restrict__ out_slots, int last)
{
    const int bs = blockIdx.x, b = bs >> 3, s = bs & 7;
    const int tid = threadIdx.x;
    __shared__ float HS[256], ynd[256], G[1536], hpr[256];
    __shared__ float hln[256], hid[512], sln[256];
    __shared__ float part[4096];
    __shared__ float red[8];
    __shared__ float dsc;

    // ---- stage A: ynd = (sum_chunk numpart)/den ; HS ; den snapshot+clear ----
    {
        const int h = tid >> 8, d2 = tid & 255;
        float a = 0.f;
        const float* np = numpart + (((size_t)b*32 + h*16)*8 + s)*256 + d2;
#pragma unroll 8
        for (int c = 0; c < 16; ++c) a += np[(size_t)c*2048];
        part[h*256 + d2] = a;
        if (tid < 256) HS[tid] = slots[(size_t)bs*256 + tid];
        if (tid == 0) { dsc = den[bs]; den[bs] = 0.f; }
    }
    __syncthreads();
    if (tid < 256) ynd[tid] = (part[tid] + part[256 + tid]) / dsc;
    __syncthreads();

    // ---- gates: fused [ynd|HS] @ WgT (N=1536, KS=2); cols<768 use Wxg fold ----
    if (tid < 384) {
        const int g8 = tid % 192, ks = tid / 192;
        const int col = g8*8;
        const float* sp = ((col < 768) ? ynd : HS) + ks*128;
        float ac[8] = {0,0,0,0,0,0,0,0};
        gemv8(WgT + (size_t)(ks*128)*1536 + col, 1536, sp, 32, ac);
#pragma unroll
        for (int j = 0; j < 8; ++j) part[ks*1536 + col + j] = ac[j];
    }
    __syncthreads();
    for (int t = tid; t < 1536; t += 512) {
        const float bias = (t < 768) ? b_ih[t] : b_hh[t - 768];
        G[t] = part[t] + part[1536 + t] + bias;
    }
    __syncthreads();

    // ---- GRU -> hpr ----
    if (tid < 256) {
        const float r = 1.f/(1.f + expf(-(G[tid]       + G[768  + tid])));
        const float z = 1.f/(1.f + expf(-(G[256 + tid] + G[1024 + tid])));
        const float n = tanhf(G[512 + tid] + r*G[1280 + tid]);
        hpr[tid] = (1.f - z)*n + z*HS[tid];
    }
    __syncthreads();

    // ---- LN_m -> hln ----
    if (tid < 256) {
        const float v = hpr[tid];
        float s1 = v, s2 = v*v;
#pragma unroll
        for (int m = 32; m >= 1; m >>= 1) { s1 += __shfl_xor(s1, m); s2 += __shfl_xor(s2, m); }
        if ((tid & 63) == 0) { red[tid >> 6] = s1; red[4 + (tid >> 6)] = s2; }
    }
    __syncthreads();
    if (tid < 256) {
        const float mean = (red[0]+red[1]+red[2]+red[3])*(1.f/256.f);
        const float var  = (red[4]+red[5]+red[6]+red[7])*(1.f/256.f) - mean*mean;
        const float rstd = rsqrtf(var + 1e-5f);
        hln[tid] = (hpr[tid]-mean)*rstd*g_m[tid] + b_m[tid];
    }
    __syncthreads();

    // ---- mlp1: hid = relu(hln@W1^T + b1) : NG=64, KS=8 ----
    {
        const int g8 = tid & 63, ks = tid >> 6;
        float ac[8] = {0,0,0,0,0,0,0,0};
        gemv8(W1T + (size_t)(ks*32)*512 + g8*8, 512, hln + ks*32, 8, ac);
#pragma unroll
        for (int j = 0; j < 8; ++j) part[ks*512 + g8*8 + j] = ac[j];
    }
    __syncthreads();
    {
        float a = b1[tid];
#pragma unroll
        for (int k = 0; k < 8; ++k) a += part[k*512 + tid];
        hid[tid] = fmaxf(a, 0.f);
    }
    __syncthreads();

    // ---- mlp2: slots' = hpr + hid@W2^T + b2 : NG=32, KS=16 (K=512) ----
    {
        const int g8 = tid & 31, ks = tid >> 5;
        float ac[8] = {0,0,0,0,0,0,0,0};
        gemv8(W2T + (size_t)(ks*32)*256 + g8*8, 256, hid + ks*32, 8, ac);
#pragma unroll
        for (int j = 0; j < 8; ++j) part[ks*256 + g8*8 + j] = ac[j];
    }
    __syncthreads();
    if (tid < 256) {
        float a = 0.f;
#pragma unroll
        for (int k = 0; k < 16; ++k) a += part[k*256 + tid];
        const float val = hpr[tid] + a + b2[tid];
        HS[tid] = val;
        slots[(size_t)bs*256 + tid] = val;
        if (last) out_slots[(size_t)bs*256 + tid] = val;
    }
    __syncthreads();
    if (last) return;

    // ---- LN_s -> sln ----
    if (tid < 256) {
        const float v = HS[tid];
        float s1 = v, s2 = v*v;
#pragma unroll
        for (int m = 32; m >= 1; m >>= 1) { s1 += __shfl_xor(s1, m); s2 += __shfl_xor(s2, m); }
        if ((tid & 63) == 0) { red[tid >> 6] = s1; red[4 + (tid >> 6)] = s2; }
    }
    __syncthreads();
    if (tid < 256) {
        const float mean = (red[0]+red[1]+red[2]+red[3])*(1.f/256.f);
        const float var  = (red[4]+red[5]+red[6]+red[7])*(1.f/256.f) - mean*mean;
        const float rstd = rsqrtf(var + 1e-5f);
        sln[tid] = (HS[tid]-mean)*rstd*g_s[tid] + b_s[tid];
    }
    __syncthreads();

    // ---- q2 = sln @ Mqk : NG=32, KS=16 ----
    {
        const int g8 = tid & 31, ks = tid >> 5;
        float ac[8] = {0,0,0,0,0,0,0,0};
        gemv8(Mqk + (size_t)(ks*16)*256 + g8*8, 256, sln + ks*16, 4, ac);
#pragma unroll
        for (int j = 0; j < 8; ++j) part[ks*256 + g8*8 + j] = ac[j];
    }
    __syncthreads();
    if (tid < 256) {
        float a = 0.f;
#pragma unroll
        for (int k = 0; k < 16; ++k) a += part[k*256 + tid];
        q2bf[(size_t)bs*256 + tid] = (bf16)a;
    }
}

// ---------------- host ----------------
extern "C" void kernel_launch(void* const* d_in, const int* in_sizes, int n_in,
                              void* d_out, int out_size, void* d_ws, size_t ws_size,
                              hipStream_t stream)
{
    const float* x        = (const float*)d_in[0];
    const float* slots_in = (const float*)d_in[1];
    const float* ln_in_g  = (const float*)d_in[2];
    const float* ln_in_b  = (const float*)d_in[3];
    const float* ln_s_g   = (const float*)d_in[4];
    const float* ln_s_b   = (const float*)d_in[5];
    const float* ln_m_g   = (const float*)d_in[6];
    const float* ln_m_b   = (const float*)d_in[7];
    const float* Wq       = (const float*)d_in[8];
    const float* Wk       = (const float*)d_in[9];
    const float* Wv       = (const float*)d_in[10];
    const float* W_ih     = (const float*)d_in[11];
    const float* W_hh     = (const float*)d_in[12];
    const float* b_ih     = (const float*)d_in[13];
    const float* b_hh     = (const float*)d_in[14];
    const float* W1       = (const float*)d_in[15];
    const float* b1       = (const float*)d_in[16];
    const float* W2       = (const float*)d_in[17];
    const float* b2       = (const float*)d_in[18];

    float* out_slots  = (float*)d_out;
    float* out_logits = out_slots + 65536;
    float* out_attn   = out_logits + 1048576;

    char* w = (char*)d_ws;
    bf16*  xln     = (bf16*)w;   w += 67108864;   // [32][4096][256] bf16
    bf16*  q2bf    = (bf16*)w;   w += 131072;     // [32][8][256] bf16
    float* slots   = (float*)w;  w += 262144;
    bf16*  WgT     = (bf16*)w;   w += 786432;     // [256 k][1536 col] (Wxg | W_hh)
    bf16*  W1T     = (bf16*)w;   w += 262144;     // [256][512]
    bf16*  W2T     = (bf16*)w;   w += 262144;     // [512][256]
    bf16*  Mqk     = (bf16*)w;   w += 131072;     // [256][256]
    float* Wxg     = (float*)w;  w += 786432;     // [768][256] fp32 (W_ih@Wv)
    float* numpart = (float*)w;  w += 8388608;    // [32 b][32 chunk][8 s][256 c] f32
    float* den     = (float*)w;  w += 4096;
    if ((size_t)(w - (char*)d_ws) > ws_size) return;  // ws too small: fail visibly

    k_prep1<<<1280, 256, 0, stream>>>(slots_in, W1, W2, slots, W1T, W2T);
    k_prep2<<<1024, 256, 0, stream>>>(Wq, Wk, W_ih, Wv, Mqk, Wxg);
    k_prep3<<<1536, 256, 0, stream>>>(Wxg, W_hh, WgT);
    k_ln_in<<<32768, 256, 0, stream>>>(x, ln_in_g, ln_in_b, xln);
    k_q0<<<256, 256, 0, stream>>>(slots, Mqk, ln_s_g, ln_s_b, q2bf, den);

    for (int it = 0; it < 3; ++it) {
        const int last = (it == 2);
        k_attn<<<dim3(32, 32), 256, 0, stream>>>(xln, q2bf, numpart, den, out_logits, last);
        if (last)
            k_attnsw<<<dim3(16, 32), 256, 0, stream>>>(out_logits, den, out_attn);
        k_slot<<<256, 512, 0, stream>>>(numpart, den, slots,
                                        WgT, b_ih, b_hh,
                                        ln_m_g, ln_m_b, W1T, b1, W2T, b2,
                                        Mqk, ln_s_g, ln_s_b,
                                        q2bf, out_slots, last);
    }
}

// Round 15
// 270.738 us; speedup vs baseline: 1.2704x; 1.2704x over previous
//
#include <hip/hip_runtime.h>
#include <cstdint>
#include <cstddef>

typedef __bf16 bf16;
typedef float  f32x4  __attribute__((ext_vector_type(4)));
typedef __bf16 bf16x8 __attribute__((ext_vector_type(8)));
typedef __bf16 bf16x4 __attribute__((ext_vector_type(4)));

// ---------------- prep1: slots copy + W1T/W2T bf16 transposed [k][col] ----------
__global__ __launch_bounds__(256) void k_prep1(
    const float* __restrict__ slots_in, const float* __restrict__ W1,
    const float* __restrict__ W2,
    float* __restrict__ slots, bf16* __restrict__ W1T, bf16* __restrict__ W2T)
{
    const int i = blockIdx.x * 256 + threadIdx.x;
    if      (i <  65536) { slots[i] = slots_in[i]; }
    else if (i < 196608) { int j = i -  65536; int k = j >> 9, c = j & 511;
                           W1T[j] = (bf16)W1[c*256 + k]; }
    else if (i < 327680) { int j = i - 196608; int k = j >> 8, c = j & 255;
                           W2T[j] = (bf16)W2[c*512 + k]; }
}

// ---------------- prep2: Mqk (blocks 0-255) + Wxg = W_ih@Wv fp32 (blocks 256-1023) ----
__global__ __launch_bounds__(256) void k_prep2(
    const float* __restrict__ Wq, const float* __restrict__ Wk,
    const float* __restrict__ W_ih, const float* __restrict__ Wv,
    bf16* __restrict__ Mqk, float* __restrict__ Wxg)
{
    const int c = threadIdx.x;
    __shared__ float v[256];
    if (blockIdx.x < 256) {
        const int e = blockIdx.x;
        v[c] = Wq[(size_t)c*256 + e];
        __syncthreads();
        float a = 0.f;
#pragma unroll 8
        for (int d = 0; d < 256; ++d) a += v[d] * Wk[(size_t)d*256 + c];
        Mqk[(size_t)e*256 + c] = (bf16)(a * 0.0625f);
    } else {
        const int g = blockIdx.x - 256;
        v[c] = W_ih[(size_t)g*256 + c];
        __syncthreads();
        float a = 0.f;
#pragma unroll 8
        for (int d = 0; d < 256; ++d) a += v[d] * Wv[(size_t)d*256 + c];
        Wxg[(size_t)g*256 + c] = a;
    }
}

// ---------------- prep3: WgT[k][1536] = bf16( col<768 ? Wxg : W_hh ) ----------------
__global__ __launch_bounds__(256) void k_prep3(
    const float* __restrict__ Wxg, const float* __restrict__ W_hh,
    bf16* __restrict__ WgT)
{
    const int j = blockIdx.x * 256 + threadIdx.x;   // 0..393215
    const int k = j / 1536, col = j - k*1536;
    WgT[j] = (bf16)((col < 768) ? Wxg[(size_t)col*256 + k] : W_hh[(size_t)(col-768)*256 + k]);
}

// ---------------- K1: LayerNorm(inputs) -> xln bf16 ----------------
__global__ __launch_bounds__(256) void k_ln_in(
    const float* __restrict__ x, const float* __restrict__ g,
    const float* __restrict__ b, bf16* __restrict__ xln)
{
    const int wave = threadIdx.x >> 6, lane = threadIdx.x & 63;
    const size_t row = (size_t)blockIdx.x * 4 + wave;
    const float* xr = x + row * 256 + lane * 4;
    f32x4 v = *(const f32x4*)xr;
    float s  = v[0] + v[1] + v[2] + v[3];
    float ss = v[0]*v[0] + v[1]*v[1] + v[2]*v[2] + v[3]*v[3];
#pragma unroll
    for (int m = 32; m >= 1; m >>= 1) { s += __shfl_xor(s, m); ss += __shfl_xor(ss, m); }
    const float mean = s * (1.f/256.f);
    const float var  = ss * (1.f/256.f) - mean*mean;
    const float rstd = rsqrtf(var + 1e-5f);
    const f32x4 gg = *(const f32x4*)(g + lane*4);
    const f32x4 bb = *(const f32x4*)(b + lane*4);
    bf16x4 o;
#pragma unroll
    for (int e = 0; e < 4; ++e) o[e] = (bf16)((v[e]-mean)*rstd*gg[e] + bb[e]);
    *(bf16x4*)(xln + row*256 + lane*4) = o;
}

// gemv partial: 8 cols/thread, klen4*4 k's from wp (stride LDW), src via LDS broadcast
__device__ __forceinline__ void gemv8(const bf16* __restrict__ wp, int LDW,
                                      const float* __restrict__ sp, int klen4,
                                      float* __restrict__ ac)
{
#pragma unroll 8
    for (int k4 = 0; k4 < klen4; ++k4) {
        const f32x4 sv = *(const f32x4*)(sp + k4*4);
#pragma unroll
        for (int kk = 0; kk < 4; ++kk) {
            const bf16x8 w = *(const bf16x8*)(wp + (size_t)(k4*4+kk)*LDW);
#pragma unroll
            for (int j = 0; j < 8; ++j) ac[j] += sv[kk]*(float)w[j];
        }
    }
}

// ---------------- K_q0: q2 = LN_s(slots) @ Mqk (bf16 out) ; zero den. grid 256 ----
__global__ __launch_bounds__(256) void k_q0(
    const float* __restrict__ slots, const bf16* __restrict__ Mqk,
    const float* __restrict__ g_s, const float* __restrict__ b_s,
    bf16* __restrict__ q2bf, float* __restrict__ den)
{
    const int bs = blockIdx.x, tid = threadIdx.x;
    __shared__ float sln[256], part[2048], red[8];
    const float v0 = slots[(size_t)bs*256 + tid];
    if (tid == 0) den[bs] = 0.f;
    {
        float s1 = v0, s2 = v0*v0;
#pragma unroll
        for (int m = 32; m >= 1; m >>= 1) { s1 += __shfl_xor(s1, m); s2 += __shfl_xor(s2, m); }
        if ((tid & 63) == 0) { red[tid >> 6] = s1; red[4 + (tid >> 6)] = s2; }
    }
    __syncthreads();
    {
        const float mean = (red[0]+red[1]+red[2]+red[3])*(1.f/256.f);
        const float var  = (red[4]+red[5]+red[6]+red[7])*(1.f/256.f) - mean*mean;
        const float rstd = rsqrtf(var + 1e-5f);
        sln[tid] = (v0-mean)*rstd*g_s[tid] + b_s[tid];
    }
    __syncthreads();
    {
        const int g8 = tid & 31, ks = tid >> 5;
        float ac[8] = {0,0,0,0,0,0,0,0};
        gemv8(Mqk + (size_t)(ks*32)*256 + g8*8, 256, sln + ks*32, 8, ac);
#pragma unroll
        for (int j = 0; j < 8; ++j) part[ks*256 + g8*8 + j] = ac[j];
    }
    __syncthreads();
    {
        float a = 0.f;
#pragma unroll
        for (int k = 0; k < 8; ++k) a += part[k*256 + tid];
        q2bf[(size_t)bs*256 + tid] = (bf16)a;
    }
}

// ---------------- K_attn1: MFMA logits + in-register softmax -> abuf[t][s] ----
__global__ __launch_bounds__(256) void k_attn1(
    const bf16* __restrict__ xln, const bf16* __restrict__ q2bf,
    bf16* __restrict__ abuf, float* __restrict__ den,
    float* __restrict__ logits_out, int write_logits)
{
    const int chunk = blockIdx.x, b = blockIdx.y;
    const int wv = threadIdx.x >> 6, lane = threadIdx.x & 63;
    const int sA = lane & 15;
    const int ko = (lane >> 4) * 8;

    bf16x8 aq[8];
    if (sA < 8) {
#pragma unroll
        for (int kk = 0; kk < 8; ++kk)
            aq[kk] = *(const bf16x8*)(q2bf + (size_t)(b*8 + sA)*256 + kk*32 + ko);
    } else {
#pragma unroll
        for (int kk = 0; kk < 8; ++kk) aq[kk] = (bf16x8){0,0,0,0,0,0,0,0};
    }

    float dacc[4] = {0.f, 0.f, 0.f, 0.f};
#pragma unroll
    for (int it = 0; it < 4; ++it) {
        const int t0 = chunk*256 + wv*64 + it*16;
        f32x4 acc = {0.f, 0.f, 0.f, 0.f};
        const bf16* xp = xln + (size_t)(b*4096 + t0 + sA)*256 + ko;
#pragma unroll
        for (int kk = 0; kk < 8; ++kk) {
            const bf16x8 bfr = *(const bf16x8*)(xp + kk*32);
            acc = __builtin_amdgcn_mfma_f32_16x16x32_bf16(aq[kk], bfr, acc, 0, 0, 0);
        }
        if (lane < 32) {
            float m1 = fmaxf(fmaxf(acc[0], acc[1]), fmaxf(acc[2], acc[3]));
            const float m2 = __shfl_xor(m1, 16);
            const float mx = fmaxf(m1, m2);
            float e[4], s4 = 0.f;
#pragma unroll
            for (int r = 0; r < 4; ++r) { e[r] = expf(acc[r] - mx); s4 += e[r]; }
            const float so = __shfl_xor(s4, 16);
            const float inv = 1.f / (s4 + so);
            const int t = t0 + (lane & 15);
            bf16x4 ab;
#pragma unroll
            for (int r = 0; r < 4; ++r) {
                const float av = e[r]*inv + 1e-8f;
                dacc[r] += av;
                ab[r] = (bf16)av;
            }
            *(bf16x4*)(abuf + (size_t)(b*4096 + t)*8 + (lane >> 4)*4) = ab;
            if (write_logits) {
#pragma unroll
                for (int r = 0; r < 4; ++r)
                    logits_out[(size_t)(b*8 + (lane >> 4)*4 + r)*4096 + t] = acc[r];
            }
        }
    }
    if (lane < 32) {
#pragma unroll
        for (int r = 0; r < 4; ++r) {
            float v = dacc[r];
            v += __shfl_xor(v, 1); v += __shfl_xor(v, 2);
            v += __shfl_xor(v, 4); v += __shfl_xor(v, 8);
            if ((lane & 15) == 0) atomicAdd(&den[b*8 + (lane >> 4)*4 + r], v);
        }
    }
}

// ---------------- K_attn2: all-8-slots-per-thread; tile read once per block ----
// grid (32 chunks of 128 t, 32 b), 256 threads = (4 tg x 32 t) x (64 cg x 4 c).
// acc[8][4] statically indexed; partials reduced via 32 KB LDS (b128 clean).
__global__ __launch_bounds__(256) void k_attn2(
    const bf16* __restrict__ xln, const bf16* __restrict__ abuf,
    float* __restrict__ numpart)
{
    const int chunk = blockIdx.x, b = blockIdx.y, tid = threadIdx.x;
    __shared__ float alds[8][132];
    __shared__ __align__(16) float part[4][2048];

    if (tid < 128) {
        const bf16x8 a8 = *(const bf16x8*)(abuf + (size_t)(b*4096 + chunk*128 + tid)*8);
#pragma unroll
        for (int s = 0; s < 8; ++s) alds[s][tid] = (float)a8[s];
    }
    __syncthreads();

    const int tg = tid >> 6, cg = tid & 63;
    float acc[8][4];
#pragma unroll
    for (int s = 0; s < 8; ++s) {
#pragma unroll
        for (int j = 0; j < 4; ++j) acc[s][j] = 0.f;
    }

    const bf16* xp = xln + (size_t)(b*4096 + chunk*128 + tg*32)*256 + cg*4;
#pragma unroll 4
    for (int t = 0; t < 32; ++t) {
        const bf16x4 x4 = *(const bf16x4*)(xp + (size_t)t*256);
        float xf[4];
#pragma unroll
        for (int e = 0; e < 4; ++e) xf[e] = (float)x4[e];
#pragma unroll
        for (int s = 0; s < 8; ++s) {
            const float a = alds[s][tg*32 + t];
#pragma unroll
            for (int j = 0; j < 4; ++j) acc[s][j] += a * xf[j];
        }
    }
#pragma unroll
    for (int s = 0; s < 8; ++s) {
        const f32x4 v = {acc[s][0], acc[s][1], acc[s][2], acc[s][3]};
        *(f32x4*)&part[tg][s*256 + cg*4] = v;
    }
    __syncthreads();

    // reduce 4 t-group partials -> numpart (2 f32x4 outputs/thread)
#pragma unroll
    for (int o = 0; o < 2; ++o) {
        const int idx = (tid*2 + o)*4;          // 0..8188 step 4 over 2048 floats
        f32x4 v = *(const f32x4*)&part[0][idx];
#pragma unroll
        for (int g = 1; g < 4; ++g) v += *(const f32x4*)&part[g][idx];
        const int s = idx >> 8, c = idx & 255;
        *(f32x4*)&numpart[(((size_t)b*32 + chunk)*8 + s)*256 + c] = v;
    }
}

// ---------------- K_attnsw: attn_sw = (softmax+eps)/den ----------------
__global__ __launch_bounds__(256) void k_attnsw(
    const float* __restrict__ logits, const float* __restrict__ den,
    float* __restrict__ attn_out)
{
    const int chunk = blockIdx.x, b = blockIdx.y;
    const int t = chunk*256 + threadIdx.x;
    float l[8];
#pragma unroll
    for (int s = 0; s < 8; ++s) l[s] = logits[(size_t)(b*8 + s)*4096 + t];
    float mx = l[0];
#pragma unroll
    for (int s = 1; s < 8; ++s) mx = fmaxf(mx, l[s]);
    float e[8], sum = 0.f;
#pragma unroll
    for (int s = 0; s < 8; ++s) { e[s] = expf(l[s] - mx); sum += e[s]; }
    const float inv = 1.f/sum;
#pragma unroll
    for (int s = 0; s < 8; ++s)
        attn_out[(size_t)(b*8 + s)*4096 + t] = (e[s]*inv + 1e-8f) / den[b*8 + s];
}

// ---------------- K_slot: per-row slot chain; upd folded into WgT (Wxg) ----
__global__ __launch_bounds__(512) void k_slot(
    const float* __restrict__ numpart, float* __restrict__ den,
    float* __restrict__ slots,
    const bf16* __restrict__ WgT,
    const float* __restrict__ b_ih, const float* __restrict__ b_hh,
    const float* __restrict__ g_m, const float* __restrict__ b_m,
    const bf16* __restrict__ W1T, const float* __restrict__ b1,
    const bf16* __restrict__ W2T, const float* __restrict__ b2,
    const bf16* __restrict__ Mqk,
    const float* __restrict__ g_s, const float* __restrict__ b_s,
    bf16* __restrict__ q2bf, float* __restrict__ out_slots, int last)
{
    const int bs = blockIdx.x, b = bs >> 3, s = bs & 7;
    const int tid = threadIdx.x;
    __shared__ float HS[256], ynd[256], G[1536], hpr[256];
    __shared__ float hln[256], hid[512], sln[256];
    __shared__ float part[4096];
    __shared__ float red[8];
    __shared__ float dsc;

    // ---- stage A: ynd = (sum_chunk numpart)/den ; HS ; den snapshot+clear ----
    {
        const int h = tid >> 8, d2 = tid & 255;
        float a = 0.f;
        const float* np = numpart + (((size_t)b*32 + h*16)*8 + s)*256 + d2;
#pragma unroll 8
        for (int c = 0; c < 16; ++c) a += np[(size_t)c*2048];
        part[h*256 + d2] = a;
        if (tid < 256) HS[tid] = slots[(size_t)bs*256 + tid];
        if (tid == 0) { dsc = den[bs]; den[bs] = 0.f; }
    }
    __syncthreads();
    if (tid < 256) ynd[tid] = (part[tid] + part[256 + tid]) / dsc;
    __syncthreads();

    // ---- gates: fused [ynd|HS] @ WgT (N=1536, KS=2); cols<768 use Wxg fold ----
    if (tid < 384) {
        const int g8 = tid % 192, ks = tid / 192;
        const int col = g8*8;
        const float* sp = ((col < 768) ? ynd : HS) + ks*128;
        float ac[8] = {0,0,0,0,0,0,0,0};
        gemv8(WgT + (size_t)(ks*128)*1536 + col, 1536, sp, 32, ac);
#pragma unroll
        for (int j = 0; j < 8; ++j) part[ks*1536 + col + j] = ac[j];
    }
    __syncthreads();
    for (int t = tid; t < 1536; t += 512) {
        const float bias = (t < 768) ? b_ih[t] : b_hh[t - 768];
        G[t] = part[t] + part[1536 + t] + bias;
    }
    __syncthreads();

    // ---- GRU -> hpr ----
    if (tid < 256) {
        const float r = 1.f/(1.f + expf(-(G[tid]       + G[768  + tid])));
        const float z = 1.f/(1.f + expf(-(G[256 + tid] + G[1024 + tid])));
        const float n = tanhf(G[512 + tid] + r*G[1280 + tid]);
        hpr[tid] = (1.f - z)*n + z*HS[tid];
    }
    __syncthreads();

    // ---- LN_m -> hln ----
    if (tid < 256) {
        const float v = hpr[tid];
        float s1 = v, s2 = v*v;
#pragma unroll
        for (int m = 32; m >= 1; m >>= 1) { s1 += __shfl_xor(s1, m); s2 += __shfl_xor(s2, m); }
        if ((tid & 63) == 0) { red[tid >> 6] = s1; red[4 + (tid >> 6)] = s2; }
    }
    __syncthreads();
    if (tid < 256) {
        const float mean = (red[0]+red[1]+red[2]+red[3])*(1.f/256.f);
        const float var  = (red[4]+red[5]+red[6]+red[7])*(1.f/256.f) - mean*mean;
        const float rstd = rsqrtf(var + 1e-5f);
        hln[tid] = (hpr[tid]-mean)*rstd*g_m[tid] + b_m[tid];
    }
    __syncthreads();

    // ---- mlp1: hid = relu(hln@W1^T + b1) : NG=64, KS=8 ----
    {
        const int g8 = tid & 63, ks = tid >> 6;
        float ac[8] = {0,0,0,0,0,0,0,0};
        gemv8(W1T + (size_t)(ks*32)*512 + g8*8, 512, hln + ks*32, 8, ac);
#pragma unroll
        for (int j = 0; j < 8; ++j) part[ks*512 + g8*8 + j] = ac[j];
    }
    __syncthreads();
    {
        float a = b1[tid];
#pragma unroll
        for (int k = 0; k < 8; ++k) a += part[k*512 + tid];
        hid[tid] = fmaxf(a, 0.f);
    }
    __syncthreads();

    // ---- mlp2: slots' = hpr + hid@W2^T + b2 : NG=32, KS=16 (K=512) ----
    {
        const int g8 = tid & 31, ks = tid >> 5;
        float ac[8] = {0,0,0,0,0,0,0,0};
        gemv8(W2T + (size_t)(ks*32)*256 + g8*8, 256, hid + ks*32, 8, ac);
#pragma unroll
        for (int j = 0; j < 8; ++j) part[ks*256 + g8*8 + j] = ac[j];
    }
    __syncthreads();
    if (tid < 256) {
        float a = 0.f;
#pragma unroll
        for (int k = 0; k < 16; ++k) a += part[k*256 + tid];
        const float val = hpr[tid] + a + b2[tid];
        HS[tid] = val;
        slots[(size_t)bs*256 + tid] = val;
        if (last) out_slots[(size_t)bs*256 + tid] = val;
    }
    __syncthreads();
    if (last) return;

    // ---- LN_s -> sln ----
    if (tid < 256) {
        const float v = HS[tid];
        float s1 = v, s2 = v*v;
#pragma unroll
        for (int m = 32; m >= 1; m >>= 1) { s1 += __shfl_xor(s1, m); s2 += __shfl_xor(s2, m); }
        if ((tid & 63) == 0) { red[tid >> 6] = s1; red[4 + (tid >> 6)] = s2; }
    }
    __syncthreads();
    if (tid < 256) {
        const float mean = (red[0]+red[1]+red[2]+red[3])*(1.f/256.f);
        const float var  = (red[4]+red[5]+red[6]+red[7])*(1.f/256.f) - mean*mean;
        const float rstd = rsqrtf(var + 1e-5f);
        sln[tid] = (HS[tid]-mean)*rstd*g_s[tid] + b_s[tid];
    }
    __syncthreads();

    // ---- q2 = sln @ Mqk : NG=32, KS=16 ----
    {
        const int g8 = tid & 31, ks = tid >> 5;
        float ac[8] = {0,0,0,0,0,0,0,0};
        gemv8(Mqk + (size_t)(ks*16)*256 + g8*8, 256, sln + ks*16, 4, ac);
#pragma unroll
        for (int j = 0; j < 8; ++j) part[ks*256 + g8*8 + j] = ac[j];
    }
    __syncthreads();
    if (tid < 256) {
        float a = 0.f;
#pragma unroll
        for (int k = 0; k < 16; ++k) a += part[k*256 + tid];
        q2bf[(size_t)bs*256 + tid] = (bf16)a;
    }
}

// ---------------- host ----------------
extern "C" void kernel_launch(void* const* d_in, const int* in_sizes, int n_in,
                              void* d_out, int out_size, void* d_ws, size_t ws_size,
                              hipStream_t stream)
{
    const float* x        = (const float*)d_in[0];
    const float* slots_in = (const float*)d_in[1];
    const float* ln_in_g  = (const float*)d_in[2];
    const float* ln_in_b  = (const float*)d_in[3];
    const float* ln_s_g   = (const float*)d_in[4];
    const float* ln_s_b   = (const float*)d_in[5];
    const float* ln_m_g   = (const float*)d_in[6];
    const float* ln_m_b   = (const float*)d_in[7];
    const float* Wq       = (const float*)d_in[8];
    const float* Wk       = (const float*)d_in[9];
    const float* Wv       = (const float*)d_in[10];
    const float* W_ih     = (const float*)d_in[11];
    const float* W_hh     = (const float*)d_in[12];
    const float* b_ih     = (const float*)d_in[13];
    const float* b_hh     = (const float*)d_in[14];
    const float* W1       = (const float*)d_in[15];
    const float* b1       = (const float*)d_in[16];
    const float* W2       = (const float*)d_in[17];
    const float* b2       = (const float*)d_in[18];

    float* out_slots  = (float*)d_out;
    float* out_logits = out_slots + 65536;
    float* out_attn   = out_logits + 1048576;

    char* w = (char*)d_ws;
    bf16*  xln     = (bf16*)w;   w += 67108864;   // [32][4096][256] bf16
    bf16*  q2bf    = (bf16*)w;   w += 131072;     // [32][8][256] bf16
    bf16*  abuf    = (bf16*)w;   w += 2097152;    // [32][4096][8] bf16 (token-major)
    float* slots   = (float*)w;  w += 262144;
    bf16*  WgT     = (bf16*)w;   w += 786432;     // [256 k][1536 col] (Wxg | W_hh)
    bf16*  W1T     = (bf16*)w;   w += 262144;     // [256][512]
    bf16*  W2T     = (bf16*)w;   w += 262144;     // [512][256]
    bf16*  Mqk     = (bf16*)w;   w += 131072;     // [256][256]
    float* Wxg     = (float*)w;  w += 786432;     // [768][256] fp32 (W_ih@Wv)
    float* numpart = (float*)w;  w += 8388608;    // [32 b][32 chunk][8 s][256 c] f32
    float* den     = (float*)w;  w += 4096;
    if ((size_t)(w - (char*)d_ws) > ws_size) return;  // ws too small: fail visibly

    k_prep1<<<1280, 256, 0, stream>>>(slots_in, W1, W2, slots, W1T, W2T);
    k_prep2<<<1024, 256, 0, stream>>>(Wq, Wk, W_ih, Wv, Mqk, Wxg);
    k_prep3<<<1536, 256, 0, stream>>>(Wxg, W_hh, WgT);
    k_ln_in<<<32768, 256, 0, stream>>>(x, ln_in_g, ln_in_b, xln);
    k_q0<<<256, 256, 0, stream>>>(slots, Mqk, ln_s_g, ln_s_b, q2bf, den);

    for (int it = 0; it < 3; ++it) {
        const int last = (it == 2);
        k_attn1<<<dim3(16, 32), 256, 0, stream>>>(xln, q2bf, abuf, den, out_logits, last);
        k_attn2<<<dim3(32, 32), 256, 0, stream>>>(xln, abuf, numpart);
        if (last)
            k_attnsw<<<dim3(16, 32), 256, 0, stream>>>(out_logits, den, out_attn);
        k_slot<<<256, 512, 0, stream>>>(numpart, den, slots,
                                        WgT, b_ih, b_hh,
                                        ln_m_g, ln_m_b, W1T, b1, W2T, b2,
                                        Mqk, ln_s_g, ln_s_b,
                                        q2bf, out_slots, last);
    }
}

// Round 16
// 247.948 us; speedup vs baseline: 1.3872x; 1.0919x over previous
//
#include <hip/hip_runtime.h>
#include <cstdint>
#include <cstddef>

typedef __bf16 bf16;
typedef float  f32x4  __attribute__((ext_vector_type(4)));
typedef __bf16 bf16x8 __attribute__((ext_vector_type(8)));
typedef __bf16 bf16x4 __attribute__((ext_vector_type(4)));

// ---------------- prep1: slots copy + W1T/W2T bf16 transposed [k][col] ----------
__global__ __launch_bounds__(256) void k_prep1(
    const float* __restrict__ slots_in, const float* __restrict__ W1,
    const float* __restrict__ W2,
    float* __restrict__ slots, bf16* __restrict__ W1T, bf16* __restrict__ W2T)
{
    const int i = blockIdx.x * 256 + threadIdx.x;
    if      (i <  65536) { slots[i] = slots_in[i]; }
    else if (i < 196608) { int j = i -  65536; int k = j >> 9, c = j & 511;
                           W1T[j] = (bf16)W1[c*256 + k]; }
    else if (i < 327680) { int j = i - 196608; int k = j >> 8, c = j & 255;
                           W2T[j] = (bf16)W2[c*512 + k]; }
}

// ---------------- prep2: Mqk (blocks 0-255) + Wxg = W_ih@Wv fp32 (blocks 256-1023) ----
__global__ __launch_bounds__(256) void k_prep2(
    const float* __restrict__ Wq, const float* __restrict__ Wk,
    const float* __restrict__ W_ih, const float* __restrict__ Wv,
    bf16* __restrict__ Mqk, float* __restrict__ Wxg)
{
    const int c = threadIdx.x;
    __shared__ float v[256];
    if (blockIdx.x < 256) {
        const int e = blockIdx.x;
        v[c] = Wq[(size_t)c*256 + e];
        __syncthreads();
        float a = 0.f;
#pragma unroll 8
        for (int d = 0; d < 256; ++d) a += v[d] * Wk[(size_t)d*256 + c];
        Mqk[(size_t)e*256 + c] = (bf16)(a * 0.0625f);
    } else {
        const int g = blockIdx.x - 256;
        v[c] = W_ih[(size_t)g*256 + c];
        __syncthreads();
        float a = 0.f;
#pragma unroll 8
        for (int d = 0; d < 256; ++d) a += v[d] * Wv[(size_t)d*256 + c];
        Wxg[(size_t)g*256 + c] = a;
    }
}

// ---------------- prep3: WgT[k][1536] = bf16( col<768 ? Wxg : W_hh ) ----------------
__global__ __launch_bounds__(256) void k_prep3(
    const float* __restrict__ Wxg, const float* __restrict__ W_hh,
    bf16* __restrict__ WgT)
{
    const int j = blockIdx.x * 256 + threadIdx.x;   // 0..393215
    const int k = j / 1536, col = j - k*1536;
    WgT[j] = (bf16)((col < 768) ? Wxg[(size_t)col*256 + k] : W_hh[(size_t)(col-768)*256 + k]);
}

// ---------------- K1: LayerNorm(inputs) -> xln bf16 ----------------
__global__ __launch_bounds__(256) void k_ln_in(
    const float* __restrict__ x, const float* __restrict__ g,
    const float* __restrict__ b, bf16* __restrict__ xln)
{
    const int wave = threadIdx.x >> 6, lane = threadIdx.x & 63;
    const size_t row = (size_t)blockIdx.x * 4 + wave;
    const float* xr = x + row * 256 + lane * 4;
    f32x4 v = *(const f32x4*)xr;
    float s  = v[0] + v[1] + v[2] + v[3];
    float ss = v[0]*v[0] + v[1]*v[1] + v[2]*v[2] + v[3]*v[3];
#pragma unroll
    for (int m = 32; m >= 1; m >>= 1) { s += __shfl_xor(s, m); ss += __shfl_xor(ss, m); }
    const float mean = s * (1.f/256.f);
    const float var  = ss * (1.f/256.f) - mean*mean;
    const float rstd = rsqrtf(var + 1e-5f);
    const f32x4 gg = *(const f32x4*)(g + lane*4);
    const f32x4 bb = *(const f32x4*)(b + lane*4);
    bf16x4 o;
#pragma unroll
    for (int e = 0; e < 4; ++e) o[e] = (bf16)((v[e]-mean)*rstd*gg[e] + bb[e]);
    *(bf16x4*)(xln + row*256 + lane*4) = o;
}

// gemv partial: 8 cols/thread, klen4*4 k's from wp (stride LDW), src via LDS broadcast
__device__ __forceinline__ void gemv8(const bf16* __restrict__ wp, int LDW,
                                      const float* __restrict__ sp, int klen4,
                                      float* __restrict__ ac)
{
#pragma unroll 8
    for (int k4 = 0; k4 < klen4; ++k4) {
        const f32x4 sv = *(const f32x4*)(sp + k4*4);
#pragma unroll
        for (int kk = 0; kk < 4; ++kk) {
            const bf16x8 w = *(const bf16x8*)(wp + (size_t)(k4*4+kk)*LDW);
#pragma unroll
            for (int j = 0; j < 8; ++j) ac[j] += sv[kk]*(float)w[j];
        }
    }
}

// ---------------- K_q0: q2 = LN_s(slots) @ Mqk (bf16 out) ; zero den. grid 256 ----
__global__ __launch_bounds__(256) void k_q0(
    const float* __restrict__ slots, const bf16* __restrict__ Mqk,
    const float* __restrict__ g_s, const float* __restrict__ b_s,
    bf16* __restrict__ q2bf, float* __restrict__ den)
{
    const int bs = blockIdx.x, tid = threadIdx.x;
    __shared__ float sln[256], part[2048], red[8];
    const float v0 = slots[(size_t)bs*256 + tid];
    if (tid == 0) den[bs] = 0.f;
    {
        float s1 = v0, s2 = v0*v0;
#pragma unroll
        for (int m = 32; m >= 1; m >>= 1) { s1 += __shfl_xor(s1, m); s2 += __shfl_xor(s2, m); }
        if ((tid & 63) == 0) { red[tid >> 6] = s1; red[4 + (tid >> 6)] = s2; }
    }
    __syncthreads();
    {
        const float mean = (red[0]+red[1]+red[2]+red[3])*(1.f/256.f);
        const float var  = (red[4]+red[5]+red[6]+red[7])*(1.f/256.f) - mean*mean;
        const float rstd = rsqrtf(var + 1e-5f);
        sln[tid] = (v0-mean)*rstd*g_s[tid] + b_s[tid];
    }
    __syncthreads();
    {
        const int g8 = tid & 31, ks = tid >> 5;
        float ac[8] = {0,0,0,0,0,0,0,0};
        gemv8(Mqk + (size_t)(ks*32)*256 + g8*8, 256, sln + ks*32, 8, ac);
#pragma unroll
        for (int j = 0; j < 8; ++j) part[ks*256 + g8*8 + j] = ac[j];
    }
    __syncthreads();
    {
        float a = 0.f;
#pragma unroll
        for (int k = 0; k < 8; ++k) a += part[k*256 + tid];
        q2bf[(size_t)bs*256 + tid] = (bf16)a;
    }
}

// ---------------- K_attn1: MFMA logits + in-register softmax -> abuf[t][s] ----
__global__ __launch_bounds__(256) void k_attn1(
    const bf16* __restrict__ xln, const bf16* __restrict__ q2bf,
    bf16* __restrict__ abuf, float* __restrict__ den,
    float* __restrict__ logits_out, int write_logits)
{
    const int chunk = blockIdx.x, b = blockIdx.y;
    const int wv = threadIdx.x >> 6, lane = threadIdx.x & 63;
    const int sA = lane & 15;
    const int ko = (lane >> 4) * 8;

    bf16x8 aq[8];
    if (sA < 8) {
#pragma unroll
        for (int kk = 0; kk < 8; ++kk)
            aq[kk] = *(const bf16x8*)(q2bf + (size_t)(b*8 + sA)*256 + kk*32 + ko);
    } else {
#pragma unroll
        for (int kk = 0; kk < 8; ++kk) aq[kk] = (bf16x8){0,0,0,0,0,0,0,0};
    }

    float dacc[4] = {0.f, 0.f, 0.f, 0.f};
#pragma unroll
    for (int it = 0; it < 4; ++it) {
        const int t0 = chunk*256 + wv*64 + it*16;
        f32x4 acc = {0.f, 0.f, 0.f, 0.f};
        const bf16* xp = xln + (size_t)(b*4096 + t0 + sA)*256 + ko;
#pragma unroll
        for (int kk = 0; kk < 8; ++kk) {
            const bf16x8 bfr = *(const bf16x8*)(xp + kk*32);
            acc = __builtin_amdgcn_mfma_f32_16x16x32_bf16(aq[kk], bfr, acc, 0, 0, 0);
        }
        if (lane < 32) {
            float m1 = fmaxf(fmaxf(acc[0], acc[1]), fmaxf(acc[2], acc[3]));
            const float m2 = __shfl_xor(m1, 16);
            const float mx = fmaxf(m1, m2);
            float e[4], s4 = 0.f;
#pragma unroll
            for (int r = 0; r < 4; ++r) { e[r] = expf(acc[r] - mx); s4 += e[r]; }
            const float so = __shfl_xor(s4, 16);
            const float inv = 1.f / (s4 + so);
            const int t = t0 + (lane & 15);
            bf16x4 ab;
#pragma unroll
            for (int r = 0; r < 4; ++r) {
                const float av = e[r]*inv + 1e-8f;
                dacc[r] += av;
                ab[r] = (bf16)av;
            }
            *(bf16x4*)(abuf + (size_t)(b*4096 + t)*8 + (lane >> 4)*4) = ab;
            if (write_logits) {
#pragma unroll
                for (int r = 0; r < 4; ++r)
                    logits_out[(size_t)(b*8 + (lane >> 4)*4 + r)*4096 + t] = acc[r];
            }
        }
    }
    if (lane < 32) {
#pragma unroll
        for (int r = 0; r < 4; ++r) {
            float v = dacc[r];
            v += __shfl_xor(v, 1); v += __shfl_xor(v, 2);
            v += __shfl_xor(v, 4); v += __shfl_xor(v, 8);
            if ((lane & 15) == 0) atomicAdd(&den[b*8 + (lane >> 4)*4 + r], v);
        }
    }
}

// ---------------- K_attn2: all-8-slots-per-thread; tile read once per block ----
__global__ __launch_bounds__(256) void k_attn2(
    const bf16* __restrict__ xln, const bf16* __restrict__ abuf,
    float* __restrict__ numpart)
{
    const int chunk = blockIdx.x, b = blockIdx.y, tid = threadIdx.x;
    __shared__ float alds[8][132];
    __shared__ __align__(16) float part[4][2048];

    if (tid < 128) {
        const bf16x8 a8 = *(const bf16x8*)(abuf + (size_t)(b*4096 + chunk*128 + tid)*8);
#pragma unroll
        for (int s = 0; s < 8; ++s) alds[s][tid] = (float)a8[s];
    }
    __syncthreads();

    const int tg = tid >> 6, cg = tid & 63;
    float acc[8][4];
#pragma unroll
    for (int s = 0; s < 8; ++s) {
#pragma unroll
        for (int j = 0; j < 4; ++j) acc[s][j] = 0.f;
    }

    const bf16* xp = xln + (size_t)(b*4096 + chunk*128 + tg*32)*256 + cg*4;
#pragma unroll 4
    for (int t = 0; t < 32; ++t) {
        const bf16x4 x4 = *(const bf16x4*)(xp + (size_t)t*256);
        float xf[4];
#pragma unroll
        for (int e = 0; e < 4; ++e) xf[e] = (float)x4[e];
#pragma unroll
        for (int s = 0; s < 8; ++s) {
            const float a = alds[s][tg*32 + t];
#pragma unroll
            for (int j = 0; j < 4; ++j) acc[s][j] += a * xf[j];
        }
    }
#pragma unroll
    for (int s = 0; s < 8; ++s) {
        const f32x4 v = {acc[s][0], acc[s][1], acc[s][2], acc[s][3]};
        *(f32x4*)&part[tg][s*256 + cg*4] = v;
    }
    __syncthreads();

#pragma unroll
    for (int o = 0; o < 2; ++o) {
        const int idx = (tid*2 + o)*4;
        f32x4 v = *(const f32x4*)&part[0][idx];
#pragma unroll
        for (int g = 1; g < 4; ++g) v += *(const f32x4*)&part[g][idx];
        const int s = idx >> 8, c = idx & 255;
        *(f32x4*)&numpart[(((size_t)b*32 + chunk)*8 + s)*256 + c] = v;
    }
}

// ---------------- K_attnsw: attn_sw = (softmax+eps)/den ----------------
__global__ __launch_bounds__(256) void k_attnsw(
    const float* __restrict__ logits, const float* __restrict__ den,
    float* __restrict__ attn_out)
{
    const int chunk = blockIdx.x, b = blockIdx.y;
    const int t = chunk*256 + threadIdx.x;
    float l[8];
#pragma unroll
    for (int s = 0; s < 8; ++s) l[s] = logits[(size_t)(b*8 + s)*4096 + t];
    float mx = l[0];
#pragma unroll
    for (int s = 1; s < 8; ++s) mx = fmaxf(mx, l[s]);
    float e[8], sum = 0.f;
#pragma unroll
    for (int s = 0; s < 8; ++s) { e[s] = expf(l[s] - mx); sum += e[s]; }
    const float inv = 1.f/sum;
#pragma unroll
    for (int s = 0; s < 8; ++s)
        attn_out[(size_t)(b*8 + s)*4096 + t] = (e[s]*inv + 1e-8f) / den[b*8 + s];
}

// ---------------- K_slot: 1024 threads (4 waves/SIMD); deeper K-splits ----
__global__ __launch_bounds__(1024) void k_slot(
    const float* __restrict__ numpart, float* __restrict__ den,
    float* __restrict__ slots,
    const bf16* __restrict__ WgT,
    const float* __restrict__ b_ih, const float* __restrict__ b_hh,
    const float* __restrict__ g_m, const float* __restrict__ b_m,
    const bf16* __restrict__ W1T, const float* __restrict__ b1,
    const bf16* __restrict__ W2T, const float* __restrict__ b2,
    const bf16* __restrict__ Mqk,
    const float* __restrict__ g_s, const float* __restrict__ b_s,
    bf16* __restrict__ q2bf, float* __restrict__ out_slots, int last)
{
    const int bs = blockIdx.x, b = bs >> 3, s = bs & 7;
    const int tid = threadIdx.x;
    __shared__ float HS[256], ynd[256], G[1536], hpr[256];
    __shared__ float hln[256], hid[512], sln[256];
    __shared__ __align__(16) float part[8192];   // 32 KB
    __shared__ float red[8];
    __shared__ float dsc;

    // ---- stage A: ynd = (sum_chunk numpart)/den ; HS ; den snapshot+clear ----
    {
        const int h = tid >> 8, d2 = tid & 255;   // 4 h-groups x 8 chunks
        float a = 0.f;
        const float* np = numpart + (((size_t)b*32 + h*8)*8 + s)*256 + d2;
#pragma unroll
        for (int c = 0; c < 8; ++c) a += np[(size_t)c*2048];
        part[h*256 + d2] = a;
        if (tid < 256) HS[tid] = slots[(size_t)bs*256 + tid];
        if (tid == 0) { dsc = den[bs]; den[bs] = 0.f; }
    }
    __syncthreads();
    if (tid < 256)
        ynd[tid] = (part[tid] + part[256 + tid] + part[512 + tid] + part[768 + tid]) / dsc;
    __syncthreads();

    // ---- gates: [ynd|HS] @ WgT : 192 groups x KS=4 (64 k each), 768 threads ----
    if (tid < 768) {
        const int g8 = tid % 192, ks = tid / 192;
        const int col = g8*8;
        const float* sp = ((col < 768) ? ynd : HS) + ks*64;
        float ac[8] = {0,0,0,0,0,0,0,0};
        gemv8(WgT + (size_t)(ks*64)*1536 + col, 1536, sp, 16, ac);
#pragma unroll
        for (int j = 0; j < 8; ++j) part[ks*1536 + col + j] = ac[j];
    }
    __syncthreads();
    for (int t = tid; t < 1536; t += 1024) {
        const float bias = (t < 768) ? b_ih[t] : b_hh[t - 768];
        G[t] = part[t] + part[1536 + t] + part[3072 + t] + part[4608 + t] + bias;
    }
    __syncthreads();

    // ---- GRU -> hpr ----
    if (tid < 256) {
        const float r = 1.f/(1.f + expf(-(G[tid]       + G[768  + tid])));
        const float z = 1.f/(1.f + expf(-(G[256 + tid] + G[1024 + tid])));
        const float n = tanhf(G[512 + tid] + r*G[1280 + tid]);
        hpr[tid] = (1.f - z)*n + z*HS[tid];
    }
    __syncthreads();

    // ---- LN_m -> hln ----
    if (tid < 256) {
        const float v = hpr[tid];
        float s1 = v, s2 = v*v;
#pragma unroll
        for (int m = 32; m >= 1; m >>= 1) { s1 += __shfl_xor(s1, m); s2 += __shfl_xor(s2, m); }
        if ((tid & 63) == 0) { red[tid >> 6] = s1; red[4 + (tid >> 6)] = s2; }
    }
    __syncthreads();
    if (tid < 256) {
        const float mean = (red[0]+red[1]+red[2]+red[3])*(1.f/256.f);
        const float var  = (red[4]+red[5]+red[6]+red[7])*(1.f/256.f) - mean*mean;
        const float rstd = rsqrtf(var + 1e-5f);
        hln[tid] = (hpr[tid]-mean)*rstd*g_m[tid] + b_m[tid];
    }
    __syncthreads();

    // ---- mlp1: hid = relu(hln@W1^T + b1) : 64 groups x KS=16 (16 k each) ----
    {
        const int g8 = tid & 63, ks = tid >> 6;
        float ac[8] = {0,0,0,0,0,0,0,0};
        gemv8(W1T + (size_t)(ks*16)*512 + g8*8, 512, hln + ks*16, 4, ac);
#pragma unroll
        for (int j = 0; j < 8; ++j) part[ks*512 + g8*8 + j] = ac[j];
    }
    __syncthreads();
    if (tid < 512) {
        float a = b1[tid];
#pragma unroll
        for (int k = 0; k < 16; ++k) a += part[k*512 + tid];
        hid[tid] = fmaxf(a, 0.f);
    }
    __syncthreads();

    // ---- mlp2: slots' = hpr + hid@W2^T + b2 : 32 groups x KS=32 (16 k, K=512) ----
    {
        const int g8 = tid & 31, ks = tid >> 5;
        float ac[8] = {0,0,0,0,0,0,0,0};
        gemv8(W2T + (size_t)(ks*16)*256 + g8*8, 256, hid + ks*16, 4, ac);
#pragma unroll
        for (int j = 0; j < 8; ++j) part[ks*256 + g8*8 + j] = ac[j];
    }
    __syncthreads();
    if (tid < 256) {
        float a = 0.f;
#pragma unroll
        for (int k = 0; k < 32; ++k) a += part[k*256 + tid];
        const float val = hpr[tid] + a + b2[tid];
        HS[tid] = val;
        slots[(size_t)bs*256 + tid] = val;
        if (last) out_slots[(size_t)bs*256 + tid] = val;
    }
    __syncthreads();
    if (last) return;

    // ---- LN_s -> sln ----
    if (tid < 256) {
        const float v = HS[tid];
        float s1 = v, s2 = v*v;
#pragma unroll
        for (int m = 32; m >= 1; m >>= 1) { s1 += __shfl_xor(s1, m); s2 += __shfl_xor(s2, m); }
        if ((tid & 63) == 0) { red[tid >> 6] = s1; red[4 + (tid >> 6)] = s2; }
    }
    __syncthreads();
    if (tid < 256) {
        const float mean = (red[0]+red[1]+red[2]+red[3])*(1.f/256.f);
        const float var  = (red[4]+red[5]+red[6]+red[7])*(1.f/256.f) - mean*mean;
        const float rstd = rsqrtf(var + 1e-5f);
        sln[tid] = (HS[tid]-mean)*rstd*g_s[tid] + b_s[tid];
    }
    __syncthreads();

    // ---- q2 = sln @ Mqk : 32 groups x KS=32 (8 k each) ----
    {
        const int g8 = tid & 31, ks = tid >> 5;
        float ac[8] = {0,0,0,0,0,0,0,0};
        gemv8(Mqk + (size_t)(ks*8)*256 + g8*8, 256, sln + ks*8, 2, ac);
#pragma unroll
        for (int j = 0; j < 8; ++j) part[ks*256 + g8*8 + j] = ac[j];
    }
    __syncthreads();
    if (tid < 256) {
        float a = 0.f;
#pragma unroll
        for (int k = 0; k < 32; ++k) a += part[k*256 + tid];
        q2bf[(size_t)bs*256 + tid] = (bf16)a;
    }
}

// ---------------- host ----------------
extern "C" void kernel_launch(void* const* d_in, const int* in_sizes, int n_in,
                              void* d_out, int out_size, void* d_ws, size_t ws_size,
                              hipStream_t stream)
{
    const float* x        = (const float*)d_in[0];
    const float* slots_in = (const float*)d_in[1];
    const float* ln_in_g  = (const float*)d_in[2];
    const float* ln_in_b  = (const float*)d_in[3];
    const float* ln_s_g   = (const float*)d_in[4];
    const float* ln_s_b   = (const float*)d_in[5];
    const float* ln_m_g   = (const float*)d_in[6];
    const float* ln_m_b   = (const float*)d_in[7];
    const float* Wq       = (const float*)d_in[8];
    const float* Wk       = (const float*)d_in[9];
    const float* Wv       = (const float*)d_in[10];
    const float* W_ih     = (const float*)d_in[11];
    const float* W_hh     = (const float*)d_in[12];
    const float* b_ih     = (const float*)d_in[13];
    const float* b_hh     = (const float*)d_in[14];
    const float* W1       = (const float*)d_in[15];
    const float* b1       = (const float*)d_in[16];
    const float* W2       = (const float*)d_in[17];
    const float* b2       = (const float*)d_in[18];

    float* out_slots  = (float*)d_out;
    float* out_logits = out_slots + 65536;
    float* out_attn   = out_logits + 1048576;

    char* w = (char*)d_ws;
    bf16*  xln     = (bf16*)w;   w += 67108864;   // [32][4096][256] bf16
    bf16*  q2bf    = (bf16*)w;   w += 131072;     // [32][8][256] bf16
    bf16*  abuf    = (bf16*)w;   w += 2097152;    // [32][4096][8] bf16 (token-major)
    float* slots   = (float*)w;  w += 262144;
    bf16*  WgT     = (bf16*)w;   w += 786432;     // [256 k][1536 col] (Wxg | W_hh)
    bf16*  W1T     = (bf16*)w;   w += 262144;     // [256][512]
    bf16*  W2T     = (bf16*)w;   w += 262144;     // [512][256]
    bf16*  Mqk     = (bf16*)w;   w += 131072;     // [256][256]
    float* Wxg     = (float*)w;  w += 786432;     // [768][256] fp32 (W_ih@Wv)
    float* numpart = (float*)w;  w += 8388608;    // [32 b][32 chunk][8 s][256 c] f32
    float* den     = (float*)w;  w += 4096;
    if ((size_t)(w - (char*)d_ws) > ws_size) return;  // ws too small: fail visibly

    k_prep1<<<1280, 256, 0, stream>>>(slots_in, W1, W2, slots, W1T, W2T);
    k_prep2<<<1024, 256, 0, stream>>>(Wq, Wk, W_ih, Wv, Mqk, Wxg);
    k_prep3<<<1536, 256, 0, stream>>>(Wxg, W_hh, WgT);
    k_ln_in<<<32768, 256, 0, stream>>>(x, ln_in_g, ln_in_b, xln);
    k_q0<<<256, 256, 0, stream>>>(slots, Mqk, ln_s_g, ln_s_b, q2bf, den);

    for (int it = 0; it < 3; ++it) {
        const int last = (it == 2);
        k_attn1<<<dim3(16, 32), 256, 0, stream>>>(xln, q2bf, abuf, den, out_logits, last);
        k_attn2<<<dim3(32, 32), 256, 0, stream>>>(xln, abuf, numpart);
        if (last)
            k_attnsw<<<dim3(16, 32), 256, 0, stream>>>(out_logits, den, out_attn);
        k_slot<<<256, 1024, 0, stream>>>(numpart, den, slots,
                                         WgT, b_ih, b_hh,
                                         ln_m_g, ln_m_b, W1T, b1, W2T, b2,
                                         Mqk, ln_s_g, ln_s_b,
                                         q2bf, out_slots, last);
    }
}